// Round 1
// baseline (306.825 us; speedup 1.0000x reference)
//
#include <hip/hip_runtime.h>

typedef __attribute__((ext_vector_type(8))) short bf16x8;
typedef __attribute__((ext_vector_type(4))) float f32x4;

#define LOG2E 1.4426950408889634f

__device__ __forceinline__ unsigned short f2b(float f) {
  union { float f; unsigned u; } v; v.f = f;
  unsigned r = v.u + 0x7fffu + ((v.u >> 16) & 1u);
  return (unsigned short)(r >> 16);
}

// ---------------- cast X (fp32 -> bf16), 4 elems/thread ----------------
__global__ void cast_x_kernel(const float* __restrict__ X, unsigned short* __restrict__ Xb, int n4) {
  int i = blockIdx.x * blockDim.x + threadIdx.x;
  if (i < n4) {
    float4 v = reinterpret_cast<const float4*>(X)[i];
    ushort4 o = make_ushort4(f2b(v.x), f2b(v.y), f2b(v.z), f2b(v.w));
    reinterpret_cast<ushort4*>(Xb)[i] = o;
  }
}

// ------------- transpose+cast W [K][N] fp32 -> Wt [N][K] bf16 -------------
// block 256 = 4 waves; lane -> n, wave -> 8 k's. Reads coalesced along n.
__global__ void transpose_cast_kernel(const float* __restrict__ W, unsigned short* __restrict__ Wt,
                                      int K, int N) {
  int lane = threadIdx.x & 63;
  int wave = threadIdx.x >> 6;
  int n = blockIdx.x * 64 + lane;
  int k0 = blockIdx.y * 32 + wave * 8;
  bf16x8 v;
#pragma unroll
  for (int j = 0; j < 8; ++j) v[j] = (short)f2b(W[(size_t)(k0 + j) * N + n]);
  *reinterpret_cast<bf16x8*>(&Wt[(size_t)n * K + k0]) = v;
}

// ---------------- GEMM C = A[M,K] * Bt[N,K]^T, bf16 in, fp32 accum --------
// 128x128 tile, 4 waves, BK=32, double-buffered LDS via global_load_lds w=16.
__device__ __forceinline__ void stage_tile(const unsigned short* __restrict__ A,
                                           const unsigned short* __restrict__ Bt,
                                           int m0, int n0, int kk, int K,
                                           unsigned short* As, unsigned short* Bs, int tid) {
  int wave = tid >> 6;
  int row = tid >> 2;       // 0..63
  int chunk = tid & 3;      // 8 bf16 each
  typedef __attribute__((address_space(3))) unsigned int lds_u32;
  typedef const __attribute__((address_space(1))) unsigned int glb_u32;
  const unsigned short* ga0 = A + (size_t)(m0 + row) * K + kk + chunk * 8;
  const unsigned short* ga1 = A + (size_t)(m0 + 64 + row) * K + kk + chunk * 8;
  const unsigned short* gb0 = Bt + (size_t)(n0 + row) * K + kk + chunk * 8;
  const unsigned short* gb1 = Bt + (size_t)(n0 + 64 + row) * K + kk + chunk * 8;
  __builtin_amdgcn_global_load_lds((glb_u32*)ga0, (lds_u32*)(As + wave * 512), 16, 0, 0);
  __builtin_amdgcn_global_load_lds((glb_u32*)ga1, (lds_u32*)(As + 2048 + wave * 512), 16, 0, 0);
  __builtin_amdgcn_global_load_lds((glb_u32*)gb0, (lds_u32*)(Bs + wave * 512), 16, 0, 0);
  __builtin_amdgcn_global_load_lds((glb_u32*)gb1, (lds_u32*)(Bs + 2048 + wave * 512), 16, 0, 0);
}

// MODE 0: qkv epilogue -> QK bf16 [4096][2048] (Q scaled 0.125) + Vt bf16 [32][64][2048]
// MODE 1: fp32 out [M][N]
template <int MODE>
__launch_bounds__(256, 2)
__global__ void gemm_bt_kernel(const unsigned short* __restrict__ A,
                               const unsigned short* __restrict__ Bt,
                               void* __restrict__ Cout,
                               unsigned short* __restrict__ Vt,
                               int M, int N, int K) {
  __shared__ __align__(16) unsigned short As[2][128 * 32];
  __shared__ __align__(16) unsigned short Bs[2][128 * 32];
  const int tid = threadIdx.x;
  const int lane = tid & 63;
  const int wave = tid >> 6;
  const int wr = wave >> 1, wc = wave & 1;
  const int m0 = blockIdx.y * 128;
  const int n0 = blockIdx.x * 128;
  const int lr = lane & 15;
  const int lk = (lane >> 4) * 8;

  f32x4 zero = {0.f, 0.f, 0.f, 0.f};
  f32x4 acc[4][4];
#pragma unroll
  for (int i = 0; i < 4; ++i)
#pragma unroll
    for (int j = 0; j < 4; ++j) acc[i][j] = zero;

  const int KT = K >> 5;
  stage_tile(A, Bt, m0, n0, 0, K, As[0], Bs[0], tid);
  int buf = 0;
  for (int kt = 0; kt < KT; ++kt) {
    __syncthreads();
    if (kt + 1 < KT) stage_tile(A, Bt, m0, n0, (kt + 1) << 5, K, As[buf ^ 1], Bs[buf ^ 1], tid);
    bf16x8 af[4], bfr[4];
#pragma unroll
    for (int mf = 0; mf < 4; ++mf)
      af[mf] = *reinterpret_cast<const bf16x8*>(&As[buf][(wr * 64 + mf * 16 + lr) * 32 + lk]);
#pragma unroll
    for (int nf = 0; nf < 4; ++nf)
      bfr[nf] = *reinterpret_cast<const bf16x8*>(&Bs[buf][(wc * 64 + nf * 16 + lr) * 32 + lk]);
#pragma unroll
    for (int mf = 0; mf < 4; ++mf)
#pragma unroll
      for (int nf = 0; nf < 4; ++nf)
        acc[mf][nf] = __builtin_amdgcn_mfma_f32_16x16x32_bf16(af[mf], bfr[nf], acc[mf][nf], 0, 0, 0);
    buf ^= 1;
  }

  const int lj = (lane >> 4) * 4;  // C/D: row = lj + j, col = lr  [measured m89]
  if (MODE == 1) {
    float* C = (float*)Cout;
#pragma unroll
    for (int mf = 0; mf < 4; ++mf)
#pragma unroll
      for (int nf = 0; nf < 4; ++nf) {
        int n = n0 + wc * 64 + nf * 16 + lr;
#pragma unroll
        for (int j = 0; j < 4; ++j) {
          int m = m0 + wr * 64 + mf * 16 + lj + j;
          C[(size_t)m * N + n] = acc[mf][nf][j];
        }
      }
  } else {
    unsigned short* QK = (unsigned short*)Cout;
    if (n0 < 2048) {
      // Q (cols 0..1023, pre-scaled by 1/sqrt(64)) and K (cols 1024..2047)
#pragma unroll
      for (int mf = 0; mf < 4; ++mf)
#pragma unroll
        for (int nf = 0; nf < 4; ++nf) {
          int n = n0 + wc * 64 + nf * 16 + lr;
          float scale = (n < 1024) ? 0.125f : 1.0f;
#pragma unroll
          for (int j = 0; j < 4; ++j) {
            int m = m0 + wr * 64 + mf * 16 + lj + j;
            QK[(size_t)m * 2048 + n] = f2b(acc[mf][nf][j] * scale);
          }
        }
    } else {
      // V -> Vt[bh][d][t]; j indexes consecutive t -> 8B packed store
#pragma unroll
      for (int mf = 0; mf < 4; ++mf)
#pragma unroll
        for (int nf = 0; nf < 4; ++nf) {
          int n = n0 - 2048 + wc * 64 + nf * 16 + lr;
          int d = n & 63, h = n >> 6;
          int mbase = m0 + wr * 64 + mf * 16 + lj;
          int b = mbase >> 11, t = mbase & 2047;
          ushort4 v = make_ushort4(f2b(acc[mf][nf][0]), f2b(acc[mf][nf][1]),
                                   f2b(acc[mf][nf][2]), f2b(acc[mf][nf][3]));
          *reinterpret_cast<ushort4*>(&Vt[(((size_t)b * 16 + h) * 64 + d) * 2048 + t]) = v;
        }
    }
  }
}

// ---------------- flash attention: 4 waves/block, 16 q-rows per wave ------
__launch_bounds__(256, 2)
__global__ void attn_kernel(const unsigned short* __restrict__ QK,
                            const unsigned short* __restrict__ Vt,
                            unsigned short* __restrict__ O) {
  __shared__ __align__(16) unsigned short Plds[4][16][72];  // +8 pad vs bank stride
  const int T = 2048;
  const int tid = threadIdx.x;
  const int wave = tid >> 6;
  const int lane = tid & 63;
  const int lr = lane & 15;
  const int lhi = lane >> 4;
  const int qb = blockIdx.x & 31;   // 32 q-blocks of 64 per (b,h)
  const int bh = blockIdx.x >> 5;   // 0..31
  const int b = bh >> 4;
  const int h = bh & 15;
  const int q0 = qb * 64 + wave * 16;

  // Q fragments (Q already scaled by 1/sqrt(d))
  const unsigned short* Qp = QK + ((size_t)(b * T + q0 + lr)) * 2048 + h * 64 + lhi * 8;
  bf16x8 aq[2];
#pragma unroll
  for (int kd = 0; kd < 2; ++kd)
    aq[kd] = *reinterpret_cast<const bf16x8*>(Qp + kd * 32);

  f32x4 zero = {0.f, 0.f, 0.f, 0.f};
  f32x4 acc_o[4];
#pragma unroll
  for (int nf = 0; nf < 4; ++nf) acc_o[nf] = zero;
  float mrow[4] = {-1e30f, -1e30f, -1e30f, -1e30f};
  float lsum[4] = {0.f, 0.f, 0.f, 0.f};

  const unsigned short* Kp = QK + ((size_t)(b * T)) * 2048 + 1024 + h * 64 + lhi * 8;
  const unsigned short* Vp = Vt + ((size_t)bh * 64) * T + lhi * 8;

  const int ktmax = (q0 + 15) >> 6;
  for (int kt = 0; kt <= ktmax; ++kt) {
    const int k0 = kt << 6;
    f32x4 s[4];
#pragma unroll
    for (int nf = 0; nf < 4; ++nf) s[nf] = zero;
#pragma unroll
    for (int nf = 0; nf < 4; ++nf) {
      const unsigned short* kp = Kp + (size_t)(k0 + nf * 16 + lr) * 2048;
      bf16x8 b0 = *reinterpret_cast<const bf16x8*>(kp);
      bf16x8 b1 = *reinterpret_cast<const bf16x8*>(kp + 32);
      s[nf] = __builtin_amdgcn_mfma_f32_16x16x32_bf16(aq[0], b0, s[nf], 0, 0, 0);
      s[nf] = __builtin_amdgcn_mfma_f32_16x16x32_bf16(aq[1], b1, s[nf], 0, 0, 0);
    }
    // causal mask (only needed on the diagonal-crossing tiles)
    if (k0 + 63 > q0) {
#pragma unroll
      for (int nf = 0; nf < 4; ++nf) {
        int key = k0 + nf * 16 + lr;
#pragma unroll
        for (int j = 0; j < 4; ++j) {
          int r = q0 + lhi * 4 + j;
          if (key > r) s[nf][j] = -1e30f;
        }
      }
    }
    // row max across 64 keys: 4 frags + shfl within 16-lane group
    float pm[4];
#pragma unroll
    for (int j = 0; j < 4; ++j)
      pm[j] = fmaxf(fmaxf(s[0][j], s[1][j]), fmaxf(s[2][j], s[3][j]));
#pragma unroll
    for (int msk = 1; msk < 16; msk <<= 1)
#pragma unroll
      for (int j = 0; j < 4; ++j) pm[j] = fmaxf(pm[j], __shfl_xor(pm[j], msk));

    float fscale[4];
#pragma unroll
    for (int j = 0; j < 4; ++j) {
      float mn = fmaxf(mrow[j], pm[j]);
      fscale[j] = exp2f((mrow[j] - mn) * LOG2E);
      mrow[j] = mn;
      lsum[j] *= fscale[j];
    }
#pragma unroll
    for (int nf = 0; nf < 4; ++nf)
#pragma unroll
      for (int j = 0; j < 4; ++j) acc_o[nf][j] *= fscale[j];

    float psum[4] = {0.f, 0.f, 0.f, 0.f};
#pragma unroll
    for (int nf = 0; nf < 4; ++nf)
#pragma unroll
      for (int j = 0; j < 4; ++j) {
        float p = exp2f((s[nf][j] - mrow[j]) * LOG2E);
        s[nf][j] = p;
        psum[j] += p;
      }
#pragma unroll
    for (int msk = 1; msk < 16; msk <<= 1)
#pragma unroll
      for (int j = 0; j < 4; ++j) psum[j] += __shfl_xor(psum[j], msk);
#pragma unroll
    for (int j = 0; j < 4; ++j) lsum[j] += psum[j];

    // P (acc layout) -> LDS -> A-fragment layout. Per-wave region, no barrier
    // (divergent trip counts across waves!). DS ops are in-order per wave;
    // waitcnt + sched_barrier for safety.
#pragma unroll
    for (int nf = 0; nf < 4; ++nf)
#pragma unroll
      for (int j = 0; j < 4; ++j)
        Plds[wave][lhi * 4 + j][nf * 16 + lr] = f2b(s[nf][j]);
    __builtin_amdgcn_sched_barrier(0);
    __builtin_amdgcn_s_waitcnt(0xC07F);  // lgkmcnt(0), others max
    __builtin_amdgcn_sched_barrier(0);
    bf16x8 ap[2];
#pragma unroll
    for (int kd = 0; kd < 2; ++kd)
      ap[kd] = *reinterpret_cast<const bf16x8*>(&Plds[wave][lr][kd * 32 + lhi * 8]);
    __builtin_amdgcn_sched_barrier(0);

    // PV: B-frag from Vt[d][t] (contiguous along t)
#pragma unroll
    for (int nf = 0; nf < 4; ++nf) {
      const unsigned short* vp = Vp + (size_t)(nf * 16 + lr) * T + k0;
      bf16x8 v0 = *reinterpret_cast<const bf16x8*>(vp);
      bf16x8 v1 = *reinterpret_cast<const bf16x8*>(vp + 32);
      acc_o[nf] = __builtin_amdgcn_mfma_f32_16x16x32_bf16(ap[0], v0, acc_o[nf], 0, 0, 0);
      acc_o[nf] = __builtin_amdgcn_mfma_f32_16x16x32_bf16(ap[1], v1, acc_o[nf], 0, 0, 0);
    }
  }

  float inv[4];
#pragma unroll
  for (int j = 0; j < 4; ++j) inv[j] = 1.0f / lsum[j];
  unsigned short* Op = O + ((size_t)(b * T + q0)) * 1024 + h * 64;
#pragma unroll
  for (int nf = 0; nf < 4; ++nf)
#pragma unroll
    for (int j = 0; j < 4; ++j)
      Op[(size_t)(lhi * 4 + j) * 1024 + nf * 16 + lr] = f2b(acc_o[nf][j] * inv[j]);
}

extern "C" void kernel_launch(void* const* d_in, const int* in_sizes, int n_in,
                              void* d_out, int out_size, void* d_ws, size_t ws_size,
                              hipStream_t stream) {
  const float* X = (const float*)d_in[0];      // [2,2048,1024]
  const float* Wqkv = (const float*)d_in[1];   // [1024,3072]
  const float* Wproj = (const float*)d_in[2];  // [1024,1024]
  float* out = (float*)d_out;                  // [2,2048,1024] fp32

  char* ws = (char*)d_ws;
  unsigned short* Xb     = (unsigned short*)(ws);              //  8,388,608 B
  unsigned short* WqkvT  = (unsigned short*)(ws + 8388608);    //  6,291,456 B
  unsigned short* WprojT = (unsigned short*)(ws + 14680064);   //  2,097,152 B
  unsigned short* QKb    = (unsigned short*)(ws + 16777216);   // 16,777,216 B
  unsigned short* Vt     = (unsigned short*)(ws + 33554432);   //  8,388,608 B
  unsigned short* Ob     = (unsigned short*)(ws + 41943040);   //  8,388,608 B
  // total: 50,331,648 B

  // 1) casts
  cast_x_kernel<<<4096, 256, 0, stream>>>(X, Xb, 4194304 / 4);
  transpose_cast_kernel<<<dim3(48, 32), 256, 0, stream>>>(Wqkv, WqkvT, 1024, 3072);
  transpose_cast_kernel<<<dim3(16, 32), 256, 0, stream>>>(Wproj, WprojT, 1024, 1024);
  // 2) qkv = X @ W_qkv  (M=4096, N=3072, K=1024), split epilogue
  gemm_bt_kernel<0><<<dim3(24, 32), 256, 0, stream>>>(Xb, WqkvT, QKb, Vt, 4096, 3072, 1024);
  // 3) flash attention -> Ob [4096][1024] bf16
  attn_kernel<<<1024, 256, 0, stream>>>(QKb, Vt, Ob);
  // 4) out = Ob @ W_proj (M=4096, N=1024, K=1024), fp32 out
  gemm_bt_kernel<1><<<dim3(8, 32), 256, 0, stream>>>(Ob, WprojT, out, nullptr, 4096, 1024, 1024);
}

// Round 2
// 206.478 us; speedup vs baseline: 1.4860x; 1.4860x over previous
//
#include <hip/hip_runtime.h>

typedef __attribute__((ext_vector_type(8))) short bf16x8;
typedef __attribute__((ext_vector_type(4))) float f32x4;

#define LOG2E 1.4426950408889634f

__device__ __forceinline__ unsigned short f2b(float f) {
  union { float f; unsigned u; } v; v.f = f;
  unsigned r = v.u + 0x7fffu + ((v.u >> 16) & 1u);
  return (unsigned short)(r >> 16);
}

// ---------------- cast X (fp32 -> bf16), 4 elems/thread ----------------
__global__ void cast_x_kernel(const float* __restrict__ X, unsigned short* __restrict__ Xb, int n4) {
  int i = blockIdx.x * blockDim.x + threadIdx.x;
  if (i < n4) {
    float4 v = reinterpret_cast<const float4*>(X)[i];
    ushort4 o = make_ushort4(f2b(v.x), f2b(v.y), f2b(v.z), f2b(v.w));
    reinterpret_cast<ushort4*>(Xb)[i] = o;
  }
}

// ------------- transpose+cast W [K][N] fp32 -> Wt [N][K] bf16 -------------
__global__ void transpose_cast_kernel(const float* __restrict__ W, unsigned short* __restrict__ Wt,
                                      int K, int N) {
  int lane = threadIdx.x & 63;
  int wave = threadIdx.x >> 6;
  int n = blockIdx.x * 64 + lane;
  int k0 = blockIdx.y * 32 + wave * 8;
  bf16x8 v;
#pragma unroll
  for (int j = 0; j < 8; ++j) v[j] = (short)f2b(W[(size_t)(k0 + j) * N + n]);
  *reinterpret_cast<bf16x8*>(&Wt[(size_t)n * K + k0]) = v;
}

// ---------------- GEMM C = A[M,K] * Bt[N,K]^T, bf16 in, fp32 accum --------
__device__ __forceinline__ void stage_tile(const unsigned short* __restrict__ A,
                                           const unsigned short* __restrict__ Bt,
                                           int m0, int n0, int kk, int K,
                                           unsigned short* As, unsigned short* Bs, int tid) {
  int wave = tid >> 6;
  int row = tid >> 2;
  int chunk = tid & 3;
  typedef __attribute__((address_space(3))) unsigned int lds_u32;
  typedef const __attribute__((address_space(1))) unsigned int glb_u32;
  const unsigned short* ga0 = A + (size_t)(m0 + row) * K + kk + chunk * 8;
  const unsigned short* ga1 = A + (size_t)(m0 + 64 + row) * K + kk + chunk * 8;
  const unsigned short* gb0 = Bt + (size_t)(n0 + row) * K + kk + chunk * 8;
  const unsigned short* gb1 = Bt + (size_t)(n0 + 64 + row) * K + kk + chunk * 8;
  __builtin_amdgcn_global_load_lds((glb_u32*)ga0, (lds_u32*)(As + wave * 512), 16, 0, 0);
  __builtin_amdgcn_global_load_lds((glb_u32*)ga1, (lds_u32*)(As + 2048 + wave * 512), 16, 0, 0);
  __builtin_amdgcn_global_load_lds((glb_u32*)gb0, (lds_u32*)(Bs + wave * 512), 16, 0, 0);
  __builtin_amdgcn_global_load_lds((glb_u32*)gb1, (lds_u32*)(Bs + 2048 + wave * 512), 16, 0, 0);
}

template <int MODE>
__launch_bounds__(256, 2)
__global__ void gemm_bt_kernel(const unsigned short* __restrict__ A,
                               const unsigned short* __restrict__ Bt,
                               void* __restrict__ Cout,
                               unsigned short* __restrict__ Vt,
                               int M, int N, int K) {
  __shared__ __align__(16) unsigned short As[2][128 * 32];
  __shared__ __align__(16) unsigned short Bs[2][128 * 32];
  const int tid = threadIdx.x;
  const int lane = tid & 63;
  const int wave = tid >> 6;
  const int wr = wave >> 1, wc = wave & 1;
  const int m0 = blockIdx.y * 128;
  const int n0 = blockIdx.x * 128;
  const int lr = lane & 15;
  const int lk = (lane >> 4) * 8;

  f32x4 zero = {0.f, 0.f, 0.f, 0.f};
  f32x4 acc[4][4];
#pragma unroll
  for (int i = 0; i < 4; ++i)
#pragma unroll
    for (int j = 0; j < 4; ++j) acc[i][j] = zero;

  const int KT = K >> 5;
  stage_tile(A, Bt, m0, n0, 0, K, As[0], Bs[0], tid);
  int buf = 0;
  for (int kt = 0; kt < KT; ++kt) {
    __syncthreads();
    if (kt + 1 < KT) stage_tile(A, Bt, m0, n0, (kt + 1) << 5, K, As[buf ^ 1], Bs[buf ^ 1], tid);
    bf16x8 af[4], bfr[4];
#pragma unroll
    for (int mf = 0; mf < 4; ++mf)
      af[mf] = *reinterpret_cast<const bf16x8*>(&As[buf][(wr * 64 + mf * 16 + lr) * 32 + lk]);
#pragma unroll
    for (int nf = 0; nf < 4; ++nf)
      bfr[nf] = *reinterpret_cast<const bf16x8*>(&Bs[buf][(wc * 64 + nf * 16 + lr) * 32 + lk]);
#pragma unroll
    for (int mf = 0; mf < 4; ++mf)
#pragma unroll
      for (int nf = 0; nf < 4; ++nf)
        acc[mf][nf] = __builtin_amdgcn_mfma_f32_16x16x32_bf16(af[mf], bfr[nf], acc[mf][nf], 0, 0, 0);
    buf ^= 1;
  }

  const int lj = (lane >> 4) * 4;
  if (MODE == 1) {
    float* C = (float*)Cout;
#pragma unroll
    for (int mf = 0; mf < 4; ++mf)
#pragma unroll
      for (int nf = 0; nf < 4; ++nf) {
        int n = n0 + wc * 64 + nf * 16 + lr;
#pragma unroll
        for (int j = 0; j < 4; ++j) {
          int m = m0 + wr * 64 + mf * 16 + lj + j;
          C[(size_t)m * N + n] = acc[mf][nf][j];
        }
      }
  } else {
    unsigned short* QK = (unsigned short*)Cout;
    if (n0 < 2048) {
#pragma unroll
      for (int mf = 0; mf < 4; ++mf)
#pragma unroll
        for (int nf = 0; nf < 4; ++nf) {
          int n = n0 + wc * 64 + nf * 16 + lr;
          float scale = (n < 1024) ? 0.125f : 1.0f;
#pragma unroll
          for (int j = 0; j < 4; ++j) {
            int m = m0 + wr * 64 + mf * 16 + lj + j;
            QK[(size_t)m * 2048 + n] = f2b(acc[mf][nf][j] * scale);
          }
        }
    } else {
#pragma unroll
      for (int mf = 0; mf < 4; ++mf)
#pragma unroll
        for (int nf = 0; nf < 4; ++nf) {
          int n = n0 - 2048 + wc * 64 + nf * 16 + lr;
          int d = n & 63, h = n >> 6;
          int mbase = m0 + wr * 64 + mf * 16 + lj;
          int b = mbase >> 11, t = mbase & 2047;
          ushort4 v = make_ushort4(f2b(acc[mf][nf][0]), f2b(acc[mf][nf][1]),
                                   f2b(acc[mf][nf][2]), f2b(acc[mf][nf][3]));
          *reinterpret_cast<ushort4*>(&Vt[(((size_t)b * 16 + h) * 64 + d) * 2048 + t]) = v;
        }
    }
  }
}

// ---------------- flash attention v2: swapped QK^T, O^T accumulation -----
// 4 waves/block, each wave = one 16-row q strip. Per-lane softmax state
// (q = lane&15). P relayout via packed LDS (2x b128 write, 4x b64 read).
// K register prefetch; V loaded at top of iteration.
#define ATTN_TILE(KT, MASKED, PREF)                                                                \
  {                                                                                                \
    const int k0 = (KT) << 6;                                                                      \
    bf16x8 vf[4][2];                                                                               \
    _Pragma("unroll")                                                                              \
    for (int mf = 0; mf < 4; ++mf) {                                                               \
      const unsigned short* vp = Vbase + (size_t)(mf * 16) * 2048 + k0;                            \
      vf[mf][0] = *reinterpret_cast<const bf16x8*>(vp);                                            \
      vf[mf][1] = *reinterpret_cast<const bf16x8*>(vp + 32);                                       \
    }                                                                                              \
    f32x4 st[4];                                                                                   \
    const int nfmax = (MASKED) ? nfd : 3;                                                          \
    _Pragma("unroll")                                                                              \
    for (int nf = 0; nf < 4; ++nf) {                                                               \
      if (nf <= nfmax) {                                                                           \
        st[nf] = __builtin_amdgcn_mfma_f32_16x16x32_bf16(kf[nf][0], qf[0], zero, 0, 0, 0);         \
        st[nf] = __builtin_amdgcn_mfma_f32_16x16x32_bf16(kf[nf][1], qf[1], st[nf], 0, 0, 0);       \
      } else {                                                                                     \
        st[nf] = mneg;                                                                             \
      }                                                                                            \
    }                                                                                              \
    if (PREF) {                                                                                    \
      const unsigned short* kp = Kbase + (size_t)(((KT) + 1) << 6) * 2048;                         \
      _Pragma("unroll")                                                                            \
      for (int nf = 0; nf < 4; ++nf) {                                                             \
        const unsigned short* kq = kp + (size_t)(nf * 16) * 2048;                                  \
        kf[nf][0] = *reinterpret_cast<const bf16x8*>(kq);                                          \
        kf[nf][1] = *reinterpret_cast<const bf16x8*>(kq + 32);                                     \
      }                                                                                            \
    }                                                                                              \
    if (MASKED) {                                                                                  \
      _Pragma("unroll")                                                                            \
      for (int j = 0; j < 4; ++j)                                                                  \
        if (4 * lhi + j > lr) st[nfd][j] = -1e30f;                                                 \
    }                                                                                              \
    float pmax = -1e30f;                                                                           \
    _Pragma("unroll")                                                                              \
    for (int nf = 0; nf < 4; ++nf)                                                                 \
      _Pragma("unroll")                                                                            \
      for (int j = 0; j < 4; ++j) pmax = fmaxf(pmax, st[nf][j]);                                   \
    pmax = fmaxf(pmax, __shfl_xor(pmax, 16));                                                      \
    pmax = fmaxf(pmax, __shfl_xor(pmax, 32));                                                      \
    const float mnew = fmaxf(mrow, pmax);                                                          \
    const float fsc = exp2f((mrow - mnew) * LOG2E);                                                \
    float psum = 0.f;                                                                              \
    unsigned int W[8];                                                                             \
    _Pragma("unroll")                                                                              \
    for (int nf = 0; nf < 4; ++nf)                                                                 \
      _Pragma("unroll")                                                                            \
      for (int h2 = 0; h2 < 2; ++h2) {                                                             \
        float p0 = exp2f((st[nf][2 * h2] - mnew) * LOG2E);                                         \
        float p1 = exp2f((st[nf][2 * h2 + 1] - mnew) * LOG2E);                                     \
        psum += p0 + p1;                                                                           \
        W[nf * 2 + h2] = (unsigned)f2b(p0) | ((unsigned)f2b(p1) << 16);                            \
      }                                                                                            \
    psum += __shfl_xor(psum, 16);                                                                  \
    psum += __shfl_xor(psum, 32);                                                                  \
    lsum = lsum * fsc + psum;                                                                      \
    mrow = mnew;                                                                                   \
    _Pragma("unroll")                                                                              \
    for (int mf = 0; mf < 4; ++mf)                                                                 \
      _Pragma("unroll")                                                                            \
      for (int j = 0; j < 4; ++j) accO[mf][j] *= fsc;                                              \
    uint4 w0 = make_uint4(W[0], W[1], W[2], W[3]);                                                 \
    uint4 w1 = make_uint4(W[4], W[5], W[6], W[7]);                                                 \
    *reinterpret_cast<uint4*>(&Pw[lr][8 * lhi]) = w0;                                              \
    *reinterpret_cast<uint4*>(&Pw[lr][8 * lhi + 4]) = w1;                                          \
    __builtin_amdgcn_s_waitcnt(0xC07F); /* lgkmcnt(0) */                                           \
    __builtin_amdgcn_sched_barrier(0);                                                             \
    bf16x8 pb[2];                                                                                  \
    _Pragma("unroll")                                                                              \
    for (int kd = 0; kd < 2; ++kd) {                                                               \
      const int nfk = 2 * kd + (lhi >> 1);                                                         \
      const int c = 2 * (nfk & 1) + 4 * (nfk >> 1);                                                \
      const int s0 = 8 * ((2 * lhi) & 3) + c;                                                      \
      const int s1 = 8 * ((2 * lhi + 1) & 3) + c;                                                  \
      union { bf16x8 v; unsigned int u[4]; } pu;                                                   \
      uint2 ra = *reinterpret_cast<const uint2*>(&Pw[lr][s0]);                                     \
      uint2 rb = *reinterpret_cast<const uint2*>(&Pw[lr][s1]);                                     \
      pu.u[0] = ra.x; pu.u[1] = ra.y; pu.u[2] = rb.x; pu.u[3] = rb.y;                              \
      pb[kd] = pu.v;                                                                               \
    }                                                                                              \
    _Pragma("unroll")                                                                              \
    for (int mf = 0; mf < 4; ++mf) {                                                               \
      accO[mf] = __builtin_amdgcn_mfma_f32_16x16x32_bf16(vf[mf][0], pb[0], accO[mf], 0, 0, 0);     \
      accO[mf] = __builtin_amdgcn_mfma_f32_16x16x32_bf16(vf[mf][1], pb[1], accO[mf], 0, 0, 0);     \
    }                                                                                              \
  }

__launch_bounds__(256, 3)
__global__ void attn_kernel(const unsigned short* __restrict__ QK,
                            const unsigned short* __restrict__ Vt,
                            unsigned short* __restrict__ O) {
  __shared__ unsigned int Pl[4][16][36];  // packed P^T words, padded stride
  const int T = 2048;
  const int tid = threadIdx.x;
  const int wave = tid >> 6;
  const int lane = tid & 63;
  const int lr = lane & 15;
  const int lhi = lane >> 4;
  const int bh = blockIdx.x & 31;
  const int qgroup = 31 - (blockIdx.x >> 5);  // long blocks dispatch first
  const int b = bh >> 4, h = bh & 15;
  const int q0 = (qgroup * 4 + wave) * 16;
  const int ktmax = qgroup;
  const int nfd = wave;  // diagonal 16x16 chunk on the last tile

  const f32x4 zero = {0.f, 0.f, 0.f, 0.f};
  const f32x4 mneg = {-1e30f, -1e30f, -1e30f, -1e30f};

  // Q as B-frag: lane holds Q[q0+lr][d = lhi*8 + kd*32 + 0..7] (pre-scaled)
  const unsigned short* Qp = QK + ((size_t)(b * T + q0 + lr)) * 2048 + h * 64 + lhi * 8;
  bf16x8 qf[2] = {*reinterpret_cast<const bf16x8*>(Qp),
                  *reinterpret_cast<const bf16x8*>(Qp + 32)};

  const unsigned short* Kbase = QK + ((size_t)(b * T + lr)) * 2048 + 1024 + h * 64 + lhi * 8;
  const unsigned short* Vbase = Vt + ((size_t)(bh * 64 + lr)) * 2048 + lhi * 8;

  // initial K tile (kt=0)
  bf16x8 kf[4][2];
#pragma unroll
  for (int nf = 0; nf < 4; ++nf) {
    const unsigned short* kq = Kbase + (size_t)(nf * 16) * 2048;
    kf[nf][0] = *reinterpret_cast<const bf16x8*>(kq);
    kf[nf][1] = *reinterpret_cast<const bf16x8*>(kq + 32);
  }

  f32x4 accO[4] = {zero, zero, zero, zero};
  float mrow = -1e30f, lsum = 0.f;
  unsigned int(*Pw)[36] = Pl[wave];

  for (int kt = 0; kt < ktmax; ++kt) ATTN_TILE(kt, false, true);
  ATTN_TILE(ktmax, true, false);

  const float inv = 1.0f / lsum;
  unsigned short* Op = O + ((size_t)(b * T + q0 + lr)) * 1024 + h * 64 + 4 * lhi;
#pragma unroll
  for (int mf = 0; mf < 4; ++mf) {
    ushort4 o = make_ushort4(f2b(accO[mf][0] * inv), f2b(accO[mf][1] * inv),
                             f2b(accO[mf][2] * inv), f2b(accO[mf][3] * inv));
    *reinterpret_cast<ushort4*>(Op + 16 * mf) = o;
  }
}

extern "C" void kernel_launch(void* const* d_in, const int* in_sizes, int n_in,
                              void* d_out, int out_size, void* d_ws, size_t ws_size,
                              hipStream_t stream) {
  const float* X = (const float*)d_in[0];
  const float* Wqkv = (const float*)d_in[1];
  const float* Wproj = (const float*)d_in[2];
  float* out = (float*)d_out;

  char* ws = (char*)d_ws;
  unsigned short* Xb     = (unsigned short*)(ws);
  unsigned short* WqkvT  = (unsigned short*)(ws + 8388608);
  unsigned short* WprojT = (unsigned short*)(ws + 14680064);
  unsigned short* QKb    = (unsigned short*)(ws + 16777216);
  unsigned short* Vt     = (unsigned short*)(ws + 33554432);
  unsigned short* Ob     = (unsigned short*)(ws + 41943040);

  cast_x_kernel<<<4096, 256, 0, stream>>>(X, Xb, 4194304 / 4);
  transpose_cast_kernel<<<dim3(48, 32), 256, 0, stream>>>(Wqkv, WqkvT, 1024, 3072);
  transpose_cast_kernel<<<dim3(16, 32), 256, 0, stream>>>(Wproj, WprojT, 1024, 1024);
  gemm_bt_kernel<0><<<dim3(24, 32), 256, 0, stream>>>(Xb, WqkvT, QKb, Vt, 4096, 3072, 1024);
  attn_kernel<<<1024, 256, 0, stream>>>(QKb, Vt, Ob);
  gemm_bt_kernel<1><<<dim3(8, 32), 256, 0, stream>>>(Ob, WprojT, out, nullptr, 4096, 1024, 1024);
}